// Round 5
// baseline (319.842 us; speedup 1.0000x reference)
//
#include <hip/hip_runtime.h>

// Hierarchical sparse attention (binary tree), MI355X gfx950.
// B=4, S=4096, H=8, D=64, f32.
//
// v6: two kernels + 128B memset.
//  K1 tree_all: per (bh, pair of 32-leaf chunks) build levels 1..5 in LDS,
//     write the two level-5 roots; then atomic fan-in per bh (AGENT scope):
//     the LAST of the 64 blocks for that bh builds levels 6..11
//     global->global (L2-local, 64KB). Deadlock-free: no block ever waits.
//  K2 attn32: block = (bh, 32-query chunk). Group pg scores queries
//     {2pg, 2pg+1}, whose self-k/v and l0-sibling operands are exactly the
//     two l1 leaves the group loads anyway (registers, no re-read).
//     All global loads issued before first barrier; levels 2..4 built by
//     wave 0 using intra-wave LDS ordering (2 barriers total).
// hi layout per bh (NHI=254 rows): [0,128)=l5, [128,192)=l6, [192,224)=l7,
// [224,240)=l8, [240,248)=l9, [248,252)=l10, [252,254)=l11.

#define S 4096
#define H 8
#define D 64
#define B 4
#define NBH 32
#define NHI 254
#define SCALE 0.125f
#define ROWF 68          // padded LDS row stride in floats

__device__ inline float red16(float x) {
    x += __shfl_xor(x, 1);
    x += __shfl_xor(x, 2);
    x += __shfl_xor(x, 4);
    x += __shfl_xor(x, 8);
    return x;
}

__device__ inline float dot4(const float4 a, const float4 b) {
    return a.x * b.x + a.y * b.y + a.z * b.z + a.w * b.w;
}

// parent(k,v) from two children: softmax-weighted merge (16-lane reduce).
__device__ inline void combine(const float4 k0, const float4 k1,
                               const float4 v0, const float4 v1,
                               float4& kp, float4& vp) {
    kp.x = 0.5f * (k0.x + k1.x);
    kp.y = 0.5f * (k0.y + k1.y);
    kp.z = 0.5f * (k0.z + k1.z);
    kp.w = 0.5f * (k0.w + k1.w);
    float pss = red16(dot4(kp, kp)) * SCALE;
    float p0  = red16(dot4(kp, k0)) * SCALE;
    float p1  = red16(dot4(kp, k1)) * SCALE;
    float m  = fmaxf(pss, fmaxf(p0, p1));
    float es = __expf(pss - m), e0 = __expf(p0 - m), e1 = __expf(p1 - m);
    float inv = 1.0f / (es + e0 + e1 + 1e-9f);
    float h = 0.5f * es;
    vp.x = ((h + e0) * v0.x + (h + e1) * v1.x) * inv;
    vp.y = ((h + e0) * v0.y + (h + e1) * v1.y) * inv;
    vp.z = ((h + e0) * v0.z + (h + e1) * v1.z) * inv;
    vp.w = ((h + e0) * v0.w + (h + e1) * v1.w) * inv;
}

// K1: per (bh, pair of 32-leaf chunks): levels 1..5, write l5 roots; the
// last-arriving block per bh builds levels 6..11.
__global__ __launch_bounds__(256, 8) void tree_all(
    const float* __restrict__ k, const float* __restrict__ v,
    float* __restrict__ khi, float* __restrict__ vhi,
    int* __restrict__ cnt)
{
    __shared__ float lsk[32 * ROWF], lsv[32 * ROWF];
    __shared__ int amLast;
    const int t = threadIdx.x;
    const int sub = t & 15;
    const int pg = t >> 4;
    const int blk = blockIdx.x;
    const int pair = blk & 63;
    const int bh = blk >> 6;
    const int b = bh >> 3, h = bh & 7;
    const int csel = pg >> 3;           // 0 or 1
    const int jg = pg & 7;
    const int c = pair * 2 + csel;      // 0..127
    const int rowBase = csel * 16;

    // level 1: 16 nodes per chunk, 2 per group
#pragma unroll
    for (int r = 0; r < 2; ++r) {
        int j = jg + r * 8;
        int s0 = c * 32 + 2 * j;
        size_t a0 = ((((size_t)b * S + s0) * H + h) * D) + sub * 4;
        float4 k0 = *(const float4*)(k + a0);
        float4 k1 = *(const float4*)(k + a0 + H * D);
        float4 v0 = *(const float4*)(v + a0);
        float4 v1 = *(const float4*)(v + a0 + H * D);
        float4 kp, vp;
        combine(k0, k1, v0, v1, kp, vp);
        *(float4*)(lsk + (rowBase + j) * ROWF + sub * 4) = kp;
        *(float4*)(lsv + (rowBase + j) * ROWF + sub * 4) = vp;
    }
    __syncthreads();

    // levels 2..5 in place: after step tt, level-(1+tt) node j at row j<<tt
#pragma unroll
    for (int tt = 1; tt <= 4; ++tt) {
        int nodes = 16 >> tt;            // 8,4,2,1
        for (int j = jg; j < nodes; j += 8) {
            int r0 = rowBase + ((2 * j) << (tt - 1));
            int r1 = rowBase + ((2 * j + 1) << (tt - 1));
            float4 k0 = *(const float4*)(lsk + r0 * ROWF + sub * 4);
            float4 k1 = *(const float4*)(lsk + r1 * ROWF + sub * 4);
            float4 v0 = *(const float4*)(lsv + r0 * ROWF + sub * 4);
            float4 v1 = *(const float4*)(lsv + r1 * ROWF + sub * 4);
            float4 kp, vp;
            combine(k0, k1, v0, v1, kp, vp);
            if (tt < 4) {
                *(float4*)(lsk + (rowBase + (j << tt)) * ROWF + sub * 4) = kp;
                *(float4*)(lsv + (rowBase + (j << tt)) * ROWF + sub * 4) = vp;
            } else {
                size_t g = ((size_t)bh * NHI + c) * 64 + sub * 4;
                *(float4*)(khi + g) = kp;
                *(float4*)(vhi + g) = vp;
            }
        }
        __syncthreads();
    }

    // ---- fan-in: last block of this bh builds levels 6..11 ----
    if (t == 0) {
        __threadfence();
        int old = __hip_atomic_fetch_add(&cnt[bh], 1, __ATOMIC_ACQ_REL,
                                         __HIP_MEMORY_SCOPE_AGENT);
        amLast = (old == 63) ? 1 : 0;
    }
    __syncthreads();
    if (!amLast) return;
    __threadfence();

    size_t base = (size_t)bh * NHI * 64;
    int srcO = 0;
#pragma unroll
    for (int lvl = 0; lvl < 6; ++lvl) {
        int nodes = 64 >> lvl;           // 64,32,16,8,4,2
        int dstO = srcO + (nodes << 1);  // 128,192,224,240,248,252
        for (int j = pg; j < nodes; j += 16) {
            float4 k0 = *(const float4*)(khi + base + (size_t)(srcO + 2 * j) * 64 + sub * 4);
            float4 k1 = *(const float4*)(khi + base + (size_t)(srcO + 2 * j + 1) * 64 + sub * 4);
            float4 v0 = *(const float4*)(vhi + base + (size_t)(srcO + 2 * j) * 64 + sub * 4);
            float4 v1 = *(const float4*)(vhi + base + (size_t)(srcO + 2 * j + 1) * 64 + sub * 4);
            float4 kp, vp;
            combine(k0, k1, v0, v1, kp, vp);
            *(float4*)(khi + base + (size_t)(dstO + j) * 64 + sub * 4) = kp;
            *(float4*)(vhi + base + (size_t)(dstO + j) * 64 + sub * 4) = vp;
        }
        __syncthreads();
        srcO = dstO;
    }
}

// K2: attention. Block = (bh, 32-query chunk). Group pg -> queries 2pg,2pg+1.
__global__ __launch_bounds__(256, 7) void attn32(
    const float* __restrict__ q, const float* __restrict__ k,
    const float* __restrict__ v,
    const float* __restrict__ khi, const float* __restrict__ vhi,
    float* __restrict__ out)
{
    __shared__ float tk[30 * ROWF], tv[30 * ROWF];   // l1:0-15 l2:16-23 l3:24-27 l4:28-29
    __shared__ float pk[7 * ROWF], pv[7 * ROWF];     // path l5..11
    const int t = threadIdx.x;
    const int sub = t & 15;
    const int pg = t >> 4;
    const int blk = blockIdx.x;
    const int c32 = blk & 127;
    const int bh = blk >> 7;
    const int b = bh >> 3, h = bh & 7;

    // stage path nodes (block-uniform): groups 0..6 -> pk, 8..14 -> pv
    {
        int pl = (pg < 7) ? pg : pg - 8;
        if (pl >= 0 && pl < 7 && pg != 7 && pg != 15) {
            if ((c32 >> pl) & 1) {
                int off = 256 - (256 >> pl);     // 0,128,192,224,240,248,252
                int node = off + ((c32 >> pl) ^ 1);
                size_t a = ((size_t)bh * NHI + node) * 64 + sub * 4;
                if (pg < 7) *(float4*)(pk + pl * ROWF + sub * 4) = *(const float4*)(khi + a);
                else        *(float4*)(pv + pl * ROWF + sub * 4) = *(const float4*)(vhi + a);
            }
        }
    }

    // leaves + queries for this group's two queries (all global loads upfront)
    const int s0 = c32 * 32 + 2 * pg;
    const size_t a0 = ((((size_t)b * S + s0) * H + h) * D) + sub * 4;
    const float4 k0 = *(const float4*)(k + a0);
    const float4 k1 = *(const float4*)(k + a0 + H * D);
    const float4 v0 = *(const float4*)(v + a0);
    const float4 v1 = *(const float4*)(v + a0 + H * D);
    const float4 q0 = *(const float4*)(q + a0);
    const float4 q1 = *(const float4*)(q + a0 + H * D);

    // level 1 node pg (operands reused later as self/sibling)
    {
        float4 kp, vp;
        combine(k0, k1, v0, v1, kp, vp);
        *(float4*)(tk + pg * ROWF + sub * 4) = kp;
        *(float4*)(tv + pg * ROWF + sub * 4) = vp;
    }
    __syncthreads();

    // wave 0 builds levels 2..4 (intra-wave DS ordering; no barriers inside)
    if (pg < 4) {
#pragma unroll
        for (int u = 0; u < 2; ++u) {          // level 2: nodes 2pg, 2pg+1
            int j = 2 * pg + u;
            float4 ka = *(const float4*)(tk + (2 * j) * ROWF + sub * 4);
            float4 kb = *(const float4*)(tk + (2 * j + 1) * ROWF + sub * 4);
            float4 va = *(const float4*)(tv + (2 * j) * ROWF + sub * 4);
            float4 vb = *(const float4*)(tv + (2 * j + 1) * ROWF + sub * 4);
            float4 kp, vp;
            combine(ka, kb, va, vb, kp, vp);
            *(float4*)(tk + (16 + j) * ROWF + sub * 4) = kp;
            *(float4*)(tv + (16 + j) * ROWF + sub * 4) = vp;
        }
        {                                       // level 3: node pg
            float4 ka = *(const float4*)(tk + (16 + 2 * pg) * ROWF + sub * 4);
            float4 kb = *(const float4*)(tk + (16 + 2 * pg + 1) * ROWF + sub * 4);
            float4 va = *(const float4*)(tv + (16 + 2 * pg) * ROWF + sub * 4);
            float4 vb = *(const float4*)(tv + (16 + 2 * pg + 1) * ROWF + sub * 4);
            float4 kp, vp;
            combine(ka, kb, va, vb, kp, vp);
            *(float4*)(tk + (24 + pg) * ROWF + sub * 4) = kp;
            *(float4*)(tv + (24 + pg) * ROWF + sub * 4) = vp;
        }
        if (pg < 2) {                           // level 4: node pg
            float4 ka = *(const float4*)(tk + (24 + 2 * pg) * ROWF + sub * 4);
            float4 kb = *(const float4*)(tk + (24 + 2 * pg + 1) * ROWF + sub * 4);
            float4 va = *(const float4*)(tv + (24 + 2 * pg) * ROWF + sub * 4);
            float4 vb = *(const float4*)(tv + (24 + 2 * pg + 1) * ROWF + sub * 4);
            float4 kp, vp;
            combine(ka, kb, va, vb, kp, vp);
            *(float4*)(tk + (28 + pg) * ROWF + sub * 4) = kp;
            *(float4*)(tv + (28 + pg) * ROWF + sub * 4) = vp;
        }
    }
    __syncthreads();

    // scoring: r=0 -> even query 2pg (self=leaf0); r=1 -> odd 2pg+1
    // (self=leaf1, l0 sibling=leaf0) — all in registers.
#pragma unroll
    for (int r = 0; r < 2; ++r) {
        const int s = s0 + r;
        const float4 q4 = r ? q1 : q0;
        const float4 k4 = r ? k1 : k0;
        const float4 v4 = r ? v1 : v0;

        float ss = red16(dot4(q4, k4)) * SCALE;

        float sc[12];
        if (r) sc[0] = red16(dot4(q4, k0)) * SCALE;
        else   sc[0] = -1e38f;
#pragma unroll
        for (int l = 1; l <= 4; ++l) {
            if ((s >> l) & 1) {
                int base = 32 - (32 >> (l - 1));          // 0,16,24,28
                int loc = base + (((s >> l) ^ 1) - (c32 << (5 - l)));
                float4 kc = *(const float4*)(tk + loc * ROWF + sub * 4);
                sc[l] = red16(dot4(q4, kc)) * SCALE;
            } else sc[l] = -1e38f;
        }
#pragma unroll
        for (int l = 5; l <= 11; ++l) {
            if ((c32 >> (l - 5)) & 1) {                   // == bit l of s
                float4 kc = *(const float4*)(pk + (l - 5) * ROWF + sub * 4);
                sc[l] = red16(dot4(q4, kc)) * SCALE;
            } else sc[l] = -1e38f;
        }

        float m = ss;
#pragma unroll
        for (int l = 0; l < 12; ++l) m = fmaxf(m, sc[l]);

        float es = __expf(ss - m);
        float denom = es;
        float4 acc;
        acc.x = es * v4.x; acc.y = es * v4.y;
        acc.z = es * v4.z; acc.w = es * v4.w;

        if (r) {
            float e = __expf(sc[0] - m);
            denom += e;
            acc.x += e * v0.x; acc.y += e * v0.y;
            acc.z += e * v0.z; acc.w += e * v0.w;
        }
#pragma unroll
        for (int l = 1; l <= 4; ++l) {
            if ((s >> l) & 1) {
                int base = 32 - (32 >> (l - 1));
                int loc = base + (((s >> l) ^ 1) - (c32 << (5 - l)));
                float4 vc = *(const float4*)(tv + loc * ROWF + sub * 4);
                float e = __expf(sc[l] - m);
                denom += e;
                acc.x += e * vc.x; acc.y += e * vc.y;
                acc.z += e * vc.z; acc.w += e * vc.w;
            }
        }
#pragma unroll
        for (int l = 5; l <= 11; ++l) {
            if ((c32 >> (l - 5)) & 1) {
                float4 vc = *(const float4*)(pv + (l - 5) * ROWF + sub * 4);
                float e = __expf(sc[l] - m);
                denom += e;
                acc.x += e * vc.x; acc.y += e * vc.y;
                acc.z += e * vc.z; acc.w += e * vc.w;
            }
        }
        float inv = 1.0f / denom;
        float4 o;
        o.x = acc.x * inv; o.y = acc.y * inv;
        o.z = acc.z * inv; o.w = acc.w * inv;
        *(float4*)(out + a0 + r * H * D) = o;
    }
}

extern "C" void kernel_launch(void* const* d_in, const int* in_sizes, int n_in,
                              void* d_out, int out_size, void* d_ws, size_t ws_size,
                              hipStream_t stream) {
    const float* q = (const float*)d_in[0];
    const float* k = (const float*)d_in[1];
    const float* v = (const float*)d_in[2];
    float* outp = (float*)d_out;
    float* khi = (float*)d_ws;                      // 32*254*64 f32 ~= 2.1 MB
    float* vhi = khi + (size_t)NBH * NHI * D;
    int* cnt = (int*)(vhi + (size_t)NBH * NHI * D); // 32 ints

    hipMemsetAsync(cnt, 0, NBH * sizeof(int), stream);
    hipLaunchKernelGGL(tree_all, dim3(NBH * 64), dim3(256), 0, stream,
                       k, v, khi, vhi, cnt);
    hipLaunchKernelGGL(attn32, dim3(NBH * 128), dim3(256), 0, stream,
                       q, k, v, khi, vhi, outp);
}

// Round 6
// 156.833 us; speedup vs baseline: 2.0394x; 2.0394x over previous
//
#include <hip/hip_runtime.h>

// Hierarchical sparse attention (binary tree), MI355X gfx950.
// B=4, S=4096, H=8, D=64, f32.
//
// v7: three kernels, no device-scope fences (v6's per-block __threadfence
// fan-in serialized ~200us of L2 writebacks on the non-coherent-XCD chip;
// kernel boundaries provide the cross-XCD release for free).
//  K1 chunk5: per (bh, pair of 32-leaf chunks) build levels 1..5 in LDS,
//     write the two level-5 roots (128 per bh).
//  K2 build_hi_half: 64 blocks; block (bh, half) builds the disjoint
//     64-root half-subtree: l6..l10 nodes of its half + its l11 node.
//  K3 attn32: block = (bh, 32-query chunk). Group pg scores queries
//     {2pg, 2pg+1}; self-k/v and l0-sibling operands are the two l1 leaves
//     the group loads anyway (registers, no re-read). All global loads
//     issued before the first barrier; levels 2..4 built by wave 0 using
//     intra-wave LDS ordering (2 barriers total).
// hi layout per bh (NHI=254 rows): [0,128)=l5, [128,192)=l6, [192,224)=l7,
// [224,240)=l8, [240,248)=l9, [248,252)=l10, [252,254)=l11.

#define S 4096
#define H 8
#define D 64
#define B 4
#define NBH 32
#define NHI 254
#define SCALE 0.125f
#define ROWF 68          // padded LDS row stride in floats

__device__ inline float red16(float x) {
    x += __shfl_xor(x, 1);
    x += __shfl_xor(x, 2);
    x += __shfl_xor(x, 4);
    x += __shfl_xor(x, 8);
    return x;
}

__device__ inline float dot4(const float4 a, const float4 b) {
    return a.x * b.x + a.y * b.y + a.z * b.z + a.w * b.w;
}

// parent(k,v) from two children: softmax-weighted merge (16-lane reduce).
__device__ inline void combine(const float4 k0, const float4 k1,
                               const float4 v0, const float4 v1,
                               float4& kp, float4& vp) {
    kp.x = 0.5f * (k0.x + k1.x);
    kp.y = 0.5f * (k0.y + k1.y);
    kp.z = 0.5f * (k0.z + k1.z);
    kp.w = 0.5f * (k0.w + k1.w);
    float pss = red16(dot4(kp, kp)) * SCALE;
    float p0  = red16(dot4(kp, k0)) * SCALE;
    float p1  = red16(dot4(kp, k1)) * SCALE;
    float m  = fmaxf(pss, fmaxf(p0, p1));
    float es = __expf(pss - m), e0 = __expf(p0 - m), e1 = __expf(p1 - m);
    float inv = 1.0f / (es + e0 + e1 + 1e-9f);
    float h = 0.5f * es;
    vp.x = ((h + e0) * v0.x + (h + e1) * v1.x) * inv;
    vp.y = ((h + e0) * v0.y + (h + e1) * v1.y) * inv;
    vp.z = ((h + e0) * v0.z + (h + e1) * v1.z) * inv;
    vp.w = ((h + e0) * v0.w + (h + e1) * v1.w) * inv;
}

// K1: per (bh, pair of 32-leaf chunks): levels 1..5 in-place, write l5 roots.
__global__ __launch_bounds__(256, 8) void chunk5(
    const float* __restrict__ k, const float* __restrict__ v,
    float* __restrict__ khi, float* __restrict__ vhi)
{
    __shared__ float lsk[32 * ROWF], lsv[32 * ROWF];
    const int t = threadIdx.x;
    const int sub = t & 15;
    const int pg = t >> 4;
    const int blk = blockIdx.x;
    const int pair = blk & 63;
    const int bh = blk >> 6;
    const int b = bh >> 3, h = bh & 7;
    const int csel = pg >> 3;           // 0 or 1
    const int jg = pg & 7;
    const int c = pair * 2 + csel;      // 0..127
    const int rowBase = csel * 16;

    // level 1: 16 nodes per chunk, 2 per group
#pragma unroll
    for (int r = 0; r < 2; ++r) {
        int j = jg + r * 8;
        int s0 = c * 32 + 2 * j;
        size_t a0 = ((((size_t)b * S + s0) * H + h) * D) + sub * 4;
        float4 k0 = *(const float4*)(k + a0);
        float4 k1 = *(const float4*)(k + a0 + H * D);
        float4 v0 = *(const float4*)(v + a0);
        float4 v1 = *(const float4*)(v + a0 + H * D);
        float4 kp, vp;
        combine(k0, k1, v0, v1, kp, vp);
        *(float4*)(lsk + (rowBase + j) * ROWF + sub * 4) = kp;
        *(float4*)(lsv + (rowBase + j) * ROWF + sub * 4) = vp;
    }
    __syncthreads();

    // levels 2..5 in place: after step tt, level-(1+tt) node j at row j<<tt
#pragma unroll
    for (int tt = 1; tt <= 4; ++tt) {
        int nodes = 16 >> tt;            // 8,4,2,1
        for (int j = jg; j < nodes; j += 8) {
            int r0 = rowBase + ((2 * j) << (tt - 1));
            int r1 = rowBase + ((2 * j + 1) << (tt - 1));
            float4 k0 = *(const float4*)(lsk + r0 * ROWF + sub * 4);
            float4 k1 = *(const float4*)(lsk + r1 * ROWF + sub * 4);
            float4 v0 = *(const float4*)(lsv + r0 * ROWF + sub * 4);
            float4 v1 = *(const float4*)(lsv + r1 * ROWF + sub * 4);
            float4 kp, vp;
            combine(k0, k1, v0, v1, kp, vp);
            if (tt < 4) {
                *(float4*)(lsk + (rowBase + (j << tt)) * ROWF + sub * 4) = kp;
                *(float4*)(lsv + (rowBase + (j << tt)) * ROWF + sub * 4) = vp;
            } else {
                size_t g = ((size_t)bh * NHI + c) * 64 + sub * 4;
                *(float4*)(khi + g) = kp;
                *(float4*)(vhi + g) = vp;
            }
        }
        __syncthreads();
    }
}

// K2: 64 blocks. Block (bh, half) builds levels 6..11 for its disjoint
// 64-root half-subtree (l11: one node per half).
__global__ __launch_bounds__(256) void build_hi_half(
    float* __restrict__ khi, float* __restrict__ vhi)
{
    __shared__ float lk[64 * ROWF], lv[64 * ROWF];
    const int t = threadIdx.x;
    const int sub = t & 15;
    const int pg = t >> 4;
    const int bh = blockIdx.x >> 1;
    const int half = blockIdx.x & 1;
    size_t base = (size_t)bh * NHI * 64;
    const int rootO = half * 64;

    // load this half's 64 l5 roots (rows rootO..rootO+63)
    for (int i = t; i < 1024; i += 256) {
        int row = i >> 4, s16 = i & 15;
        *(float4*)(lk + row * ROWF + s16 * 4) =
            *(const float4*)(khi + base + (size_t)(rootO + row) * 64 + s16 * 4);
        *(float4*)(lv + row * ROWF + s16 * 4) =
            *(const float4*)(vhi + base + (size_t)(rootO + row) * 64 + s16 * 4);
    }
    __syncthreads();

    // in-place: after step tt, level-(5+tt) local node j at LDS row j<<tt
#pragma unroll
    for (int tt = 1; tt <= 6; ++tt) {
        int nodes = 64 >> tt;                 // 32,16,8,4,2,1 (per half)
        int off = 256 - (256 >> tt);          // 128,192,224,240,248,252
        for (int j = pg; j < nodes; j += 16) {
            int r0 = (2 * j) << (tt - 1);
            int r1 = (2 * j + 1) << (tt - 1);
            float4 k0 = *(const float4*)(lk + r0 * ROWF + sub * 4);
            float4 k1 = *(const float4*)(lk + r1 * ROWF + sub * 4);
            float4 v0 = *(const float4*)(lv + r0 * ROWF + sub * 4);
            float4 v1 = *(const float4*)(lv + r1 * ROWF + sub * 4);
            float4 kp, vp;
            combine(k0, k1, v0, v1, kp, vp);
            *(float4*)(lk + (j << tt) * ROWF + sub * 4) = kp;
            *(float4*)(lv + (j << tt) * ROWF + sub * 4) = vp;
            size_t g = base + (size_t)(off + half * nodes + j) * 64 + sub * 4;
            *(float4*)(khi + g) = kp;
            *(float4*)(vhi + g) = vp;
        }
        __syncthreads();
    }
}

// K3: attention. Block = (bh, 32-query chunk). Group pg -> queries 2pg,2pg+1.
__global__ __launch_bounds__(256, 7) void attn32(
    const float* __restrict__ q, const float* __restrict__ k,
    const float* __restrict__ v,
    const float* __restrict__ khi, const float* __restrict__ vhi,
    float* __restrict__ out)
{
    __shared__ float tk[30 * ROWF], tv[30 * ROWF];   // l1:0-15 l2:16-23 l3:24-27 l4:28-29
    __shared__ float pk[7 * ROWF], pv[7 * ROWF];     // path l5..11
    const int t = threadIdx.x;
    const int sub = t & 15;
    const int pg = t >> 4;
    const int blk = blockIdx.x;
    const int c32 = blk & 127;
    const int bh = blk >> 7;
    const int b = bh >> 3, h = bh & 7;

    // stage path nodes (block-uniform): groups 0..6 -> pk, 8..14 -> pv
    {
        int pl = (pg < 7) ? pg : pg - 8;
        if (pl >= 0 && pl < 7 && pg != 7 && pg != 15) {
            if ((c32 >> pl) & 1) {
                int off = 256 - (256 >> pl);     // 0,128,192,224,240,248,252
                int node = off + ((c32 >> pl) ^ 1);
                size_t a = ((size_t)bh * NHI + node) * 64 + sub * 4;
                if (pg < 7) *(float4*)(pk + pl * ROWF + sub * 4) = *(const float4*)(khi + a);
                else        *(float4*)(pv + pl * ROWF + sub * 4) = *(const float4*)(vhi + a);
            }
        }
    }

    // leaves + queries for this group's two queries (all global loads upfront)
    const int s0 = c32 * 32 + 2 * pg;
    const size_t a0 = ((((size_t)b * S + s0) * H + h) * D) + sub * 4;
    const float4 k0 = *(const float4*)(k + a0);
    const float4 k1 = *(const float4*)(k + a0 + H * D);
    const float4 v0 = *(const float4*)(v + a0);
    const float4 v1 = *(const float4*)(v + a0 + H * D);
    const float4 q0 = *(const float4*)(q + a0);
    const float4 q1 = *(const float4*)(q + a0 + H * D);

    // level 1 node pg (operands reused later as self/sibling)
    {
        float4 kp, vp;
        combine(k0, k1, v0, v1, kp, vp);
        *(float4*)(tk + pg * ROWF + sub * 4) = kp;
        *(float4*)(tv + pg * ROWF + sub * 4) = vp;
    }
    __syncthreads();

    // wave 0 builds levels 2..4 (intra-wave DS ordering; no barriers inside)
    if (pg < 4) {
#pragma unroll
        for (int u = 0; u < 2; ++u) {          // level 2: nodes 2pg, 2pg+1
            int j = 2 * pg + u;
            float4 ka = *(const float4*)(tk + (2 * j) * ROWF + sub * 4);
            float4 kb = *(const float4*)(tk + (2 * j + 1) * ROWF + sub * 4);
            float4 va = *(const float4*)(tv + (2 * j) * ROWF + sub * 4);
            float4 vb = *(const float4*)(tv + (2 * j + 1) * ROWF + sub * 4);
            float4 kp, vp;
            combine(ka, kb, va, vb, kp, vp);
            *(float4*)(tk + (16 + j) * ROWF + sub * 4) = kp;
            *(float4*)(tv + (16 + j) * ROWF + sub * 4) = vp;
        }
        {                                       // level 3: node pg
            float4 ka = *(const float4*)(tk + (16 + 2 * pg) * ROWF + sub * 4);
            float4 kb = *(const float4*)(tk + (16 + 2 * pg + 1) * ROWF + sub * 4);
            float4 va = *(const float4*)(tv + (16 + 2 * pg) * ROWF + sub * 4);
            float4 vb = *(const float4*)(tv + (16 + 2 * pg + 1) * ROWF + sub * 4);
            float4 kp, vp;
            combine(ka, kb, va, vb, kp, vp);
            *(float4*)(tk + (24 + pg) * ROWF + sub * 4) = kp;
            *(float4*)(tv + (24 + pg) * ROWF + sub * 4) = vp;
        }
        if (pg < 2) {                           // level 4: node pg
            float4 ka = *(const float4*)(tk + (24 + 2 * pg) * ROWF + sub * 4);
            float4 kb = *(const float4*)(tk + (24 + 2 * pg + 1) * ROWF + sub * 4);
            float4 va = *(const float4*)(tv + (24 + 2 * pg) * ROWF + sub * 4);
            float4 vb = *(const float4*)(tv + (24 + 2 * pg + 1) * ROWF + sub * 4);
            float4 kp, vp;
            combine(ka, kb, va, vb, kp, vp);
            *(float4*)(tk + (28 + pg) * ROWF + sub * 4) = kp;
            *(float4*)(tv + (28 + pg) * ROWF + sub * 4) = vp;
        }
    }
    __syncthreads();

    // scoring: r=0 -> even query 2pg (self=leaf0); r=1 -> odd 2pg+1
    // (self=leaf1, l0 sibling=leaf0) — all in registers.
#pragma unroll
    for (int r = 0; r < 2; ++r) {
        const int s = s0 + r;
        const float4 q4 = r ? q1 : q0;
        const float4 k4 = r ? k1 : k0;
        const float4 v4 = r ? v1 : v0;

        float ss = red16(dot4(q4, k4)) * SCALE;

        float sc[12];
        if (r) sc[0] = red16(dot4(q4, k0)) * SCALE;
        else   sc[0] = -1e38f;
#pragma unroll
        for (int l = 1; l <= 4; ++l) {
            if ((s >> l) & 1) {
                int base = 32 - (32 >> (l - 1));          // 0,16,24,28
                int loc = base + (((s >> l) ^ 1) - (c32 << (5 - l)));
                float4 kc = *(const float4*)(tk + loc * ROWF + sub * 4);
                sc[l] = red16(dot4(q4, kc)) * SCALE;
            } else sc[l] = -1e38f;
        }
#pragma unroll
        for (int l = 5; l <= 11; ++l) {
            if ((c32 >> (l - 5)) & 1) {                   // == bit l of s
                float4 kc = *(const float4*)(pk + (l - 5) * ROWF + sub * 4);
                sc[l] = red16(dot4(q4, kc)) * SCALE;
            } else sc[l] = -1e38f;
        }

        float m = ss;
#pragma unroll
        for (int l = 0; l < 12; ++l) m = fmaxf(m, sc[l]);

        float es = __expf(ss - m);
        float denom = es;
        float4 acc;
        acc.x = es * v4.x; acc.y = es * v4.y;
        acc.z = es * v4.z; acc.w = es * v4.w;

        if (r) {
            float e = __expf(sc[0] - m);
            denom += e;
            acc.x += e * v0.x; acc.y += e * v0.y;
            acc.z += e * v0.z; acc.w += e * v0.w;
        }
#pragma unroll
        for (int l = 1; l <= 4; ++l) {
            if ((s >> l) & 1) {
                int base = 32 - (32 >> (l - 1));
                int loc = base + (((s >> l) ^ 1) - (c32 << (5 - l)));
                float4 vc = *(const float4*)(tv + loc * ROWF + sub * 4);
                float e = __expf(sc[l] - m);
                denom += e;
                acc.x += e * vc.x; acc.y += e * vc.y;
                acc.z += e * vc.z; acc.w += e * vc.w;
            }
        }
#pragma unroll
        for (int l = 5; l <= 11; ++l) {
            if ((c32 >> (l - 5)) & 1) {
                float4 vc = *(const float4*)(pv + (l - 5) * ROWF + sub * 4);
                float e = __expf(sc[l] - m);
                denom += e;
                acc.x += e * vc.x; acc.y += e * vc.y;
                acc.z += e * vc.z; acc.w += e * vc.w;
            }
        }
        float inv = 1.0f / denom;
        float4 o;
        o.x = acc.x * inv; o.y = acc.y * inv;
        o.z = acc.z * inv; o.w = acc.w * inv;
        *(float4*)(out + a0 + r * H * D) = o;
    }
}

extern "C" void kernel_launch(void* const* d_in, const int* in_sizes, int n_in,
                              void* d_out, int out_size, void* d_ws, size_t ws_size,
                              hipStream_t stream) {
    const float* q = (const float*)d_in[0];
    const float* k = (const float*)d_in[1];
    const float* v = (const float*)d_in[2];
    float* outp = (float*)d_out;
    float* khi = (float*)d_ws;                      // 32*254*64 f32 ~= 2.1 MB
    float* vhi = khi + (size_t)NBH * NHI * D;

    hipLaunchKernelGGL(chunk5, dim3(NBH * 64), dim3(256), 0, stream,
                       k, v, khi, vhi);
    hipLaunchKernelGGL(build_hi_half, dim3(NBH * 2), dim3(256), 0, stream,
                       khi, vhi);
    hipLaunchKernelGGL(attn32, dim3(NBH * 128), dim3(256), 0, stream,
                       q, k, v, khi, vhi, outp);
}